// Round 1
// baseline (836.691 us; speedup 1.0000x reference)
//
#include <hip/hip_runtime.h>

#define DEV __device__ __forceinline__

constexpr int L = 3;
constexpr int C = 64;
constexpr int H = 4;
constexpr int CP = 68;   // padded LDS stride: keeps float4 16B-aligned, spreads banks

DEV float4 ld4g(const float* p) { return *reinterpret_cast<const float4*>(p); }
DEV void st4g(float* p, float4 v) { *reinterpret_cast<float4*>(p) = v; }
DEV void fma4(float4& a, float s, float4 w) {
    a.x = fmaf(s, w.x, a.x); a.y = fmaf(s, w.y, a.y);
    a.z = fmaf(s, w.z, a.z); a.w = fmaf(s, w.w, a.w);
}

// ---------------------------------------------------------------------------
// QKV projection. Blocks [0, nkvBlocks): compute k,v rows (task space N*L).
// Blocks [nkvBlocks, ...): compute q rows (task space N, source row = n*L+L-1).
// 64 rows x 64 cols per block; 4x4 register tile per lane.
// q is pre-scaled by 1/sqrt(D) = 0.25.
// ---------------------------------------------------------------------------
__global__ __launch_bounds__(256) void qkv_kernel(
    const float* __restrict__ history,
    const float* __restrict__ Wk, const float* __restrict__ bk,
    const float* __restrict__ Wv, const float* __restrict__ bv,
    const float* __restrict__ Wq, const float* __restrict__ bq,
    float* __restrict__ kout, float* __restrict__ vout, float* __restrict__ qout,
    int N, int nkvBlocks)
{
    __shared__ float XT[C][CP];
    __shared__ float W1T[C][CP];
    __shared__ float W2T[C][CP];
    __shared__ float b1s[C], b2s[C];

    const bool isKV = (int)blockIdx.x < nkvBlocks;
    const int rowBase = (isKV ? blockIdx.x : (blockIdx.x - nkvBlocks)) * 64;
    const int totalRows = isKV ? N * L : N;
    const int tid = threadIdx.x;

    #pragma unroll
    for (int j = 0; j < 16; ++j) {
        int idx = tid + (j << 8);
        int ii = idx & 63, cc = idx >> 6;   // W[c][i] -> WT[i][c]
        if (isKV) {
            W1T[ii][cc] = Wk[idx];
            W2T[ii][cc] = Wv[idx];
        } else {
            W1T[ii][cc] = Wq[idx];
        }
    }
    if (tid < C) {
        b1s[tid] = isKV ? bk[tid] : bq[tid];
        b2s[tid] = isKV ? bv[tid] : 0.f;
    }
    #pragma unroll
    for (int j = 0; j < 4; ++j) {
        int f4 = tid + (j << 8);
        int r = f4 >> 4;
        int i0 = (f4 & 15) << 2;
        int grow = rowBase + r;
        float4 xv = make_float4(0.f, 0.f, 0.f, 0.f);
        if (grow < totalRows) {
            size_t srcRow = isKV ? (size_t)grow : ((size_t)grow * L + (L - 1));
            xv = ld4g(&history[srcRow * C + i0]);
        }
        XT[i0 + 0][r] = xv.x; XT[i0 + 1][r] = xv.y;
        XT[i0 + 2][r] = xv.z; XT[i0 + 3][r] = xv.w;
    }
    __syncthreads();

    const int lane = tid & 63;
    const int wid = tid >> 6;
    const int r0 = (wid << 4) + ((lane >> 4) << 2);  // local row base
    const int c0 = (lane & 15) << 2;                 // col base

    float4 b1 = *(const float4*)&b1s[c0];
    float4 acc1[4] = { b1, b1, b1, b1 };

    if (isKV) {
        float4 b2 = *(const float4*)&b2s[c0];
        float4 acc2[4] = { b2, b2, b2, b2 };
        for (int i = 0; i < C; ++i) {
            float4 xr = *(const float4*)&XT[i][r0];
            float4 w1 = *(const float4*)&W1T[i][c0];
            float4 w2 = *(const float4*)&W2T[i][c0];
            fma4(acc1[0], xr.x, w1); fma4(acc2[0], xr.x, w2);
            fma4(acc1[1], xr.y, w1); fma4(acc2[1], xr.y, w2);
            fma4(acc1[2], xr.z, w1); fma4(acc2[2], xr.z, w2);
            fma4(acc1[3], xr.w, w1); fma4(acc2[3], xr.w, w2);
        }
        #pragma unroll
        for (int j = 0; j < 4; ++j) {
            int grow = rowBase + r0 + j;
            if (grow < totalRows) {
                st4g(&kout[(size_t)grow * C + c0], acc1[j]);
                st4g(&vout[(size_t)grow * C + c0], acc2[j]);
            }
        }
    } else {
        for (int i = 0; i < C; ++i) {
            float4 xr = *(const float4*)&XT[i][r0];
            float4 w1 = *(const float4*)&W1T[i][c0];
            fma4(acc1[0], xr.x, w1);
            fma4(acc1[1], xr.y, w1);
            fma4(acc1[2], xr.z, w1);
            fma4(acc1[3], xr.w, w1);
        }
        #pragma unroll
        for (int j = 0; j < 4; ++j) {
            int grow = rowBase + r0 + j;
            if (grow < totalRows) {
                float4 o = acc1[j];
                o.x *= 0.25f; o.y *= 0.25f; o.z *= 0.25f; o.w *= 0.25f;
                st4g(&qout[(size_t)grow * C + c0], o);
            }
        }
    }
}

// ---------------------------------------------------------------------------
// Edge pass. 4 edges per wave, 16 lanes per edge, 4 channels (float4) per lane.
// Token softmax over L=3 per head; normalization across edges factored:
//   acc[col] += edge_msg * exp(edge_score);  den[col,h] += exp(edge_score)
// (seg_max skipped — softmax is shift-invariant; |scores| <~ 6 so exp is safe)
// ---------------------------------------------------------------------------
__global__ __launch_bounds__(256) void edge_kernel(
    const int* __restrict__ ei,
    const float* __restrict__ q, const float* __restrict__ k, const float* __restrict__ v,
    float* __restrict__ acc, float* __restrict__ den, int E)
{
    const int lane = threadIdx.x & 63;
    const int gw = blockIdx.x * 4 + (threadIdx.x >> 6);  // wave id
    const int sub = lane >> 4;    // edge within wave
    const int ld = lane & 15;     // lane within edge
    const int e = gw * 4 + sub;
    const bool act = e < E;
    const int eSafe = act ? e : 0;
    const int row = ei[eSafe];        // src
    const int col = ei[E + eSafe];    // dst
    const int c0 = ld << 2;           // channel base; head h = ld>>2

    float4 qv = ld4g(&q[(size_t)col * C + c0]);   // pre-scaled by 0.25
    const float* kb = &k[(size_t)row * (L * C)];
    const float* vb = &v[(size_t)row * (L * C)];
    float4 k0 = ld4g(kb + c0), k1 = ld4g(kb + C + c0), k2 = ld4g(kb + 2 * C + c0);

    float s0 = qv.x * k0.x + qv.y * k0.y + qv.z * k0.z + qv.w * k0.w;
    float s1 = qv.x * k1.x + qv.y * k1.y + qv.z * k1.z + qv.w * k1.w;
    float s2 = qv.x * k2.x + qv.y * k2.y + qv.z * k2.z + qv.w * k2.w;
    // reduce over the 4 lanes of this head (lane bits 0-1)
    s0 += __shfl_xor(s0, 1); s0 += __shfl_xor(s0, 2);
    s1 += __shfl_xor(s1, 1); s1 += __shfl_xor(s1, 2);
    s2 += __shfl_xor(s2, 1); s2 += __shfl_xor(s2, 2);

    float e0 = __expf(s0), e1 = __expf(s1), e2 = __expf(s2);
    float ee = fmaxf(fmaxf(e0, e1), e2);          // = exp(max score)
    float sc = ee / (e0 + e1 + e2);
    float w0 = e0 * sc, w1 = e1 * sc, w2 = e2 * sc;  // token_w * exp(edge_score)

    float4 v0 = ld4g(vb + c0), v1 = ld4g(vb + C + c0), v2 = ld4g(vb + 2 * C + c0);
    float4 m;
    m.x = w0 * v0.x + w1 * v1.x + w2 * v2.x;
    m.y = w0 * v0.y + w1 * v1.y + w2 * v2.y;
    m.z = w0 * v0.z + w1 * v1.z + w2 * v2.z;
    m.w = w0 * v0.w + w1 * v1.w + w2 * v2.w;

    if (act) {
        float* ap = &acc[(size_t)col * C + c0];
        atomicAdd(ap + 0, m.x);
        atomicAdd(ap + 1, m.y);
        atomicAdd(ap + 2, m.z);
        atomicAdd(ap + 3, m.w);
        if ((ld & 3) == 0) atomicAdd(&den[col * H + (ld >> 2)], ee);
    }
}

// ---------------------------------------------------------------------------
// Output projection: out = (acc/den) @ Wo.T + bo + current
// ---------------------------------------------------------------------------
__global__ __launch_bounds__(256) void out_kernel(
    const float* __restrict__ acc, const float* __restrict__ den,
    const float* __restrict__ history,
    const float* __restrict__ Wo, const float* __restrict__ bo,
    float* __restrict__ out, int N)
{
    __shared__ float XT[C][CP];
    __shared__ float WT[C][CP];
    __shared__ float bs[C];
    const int tid = threadIdx.x;
    const int rowBase = blockIdx.x * 64;

    #pragma unroll
    for (int j = 0; j < 16; ++j) {
        int idx = tid + (j << 8);
        WT[idx & 63][idx >> 6] = Wo[idx];
    }
    if (tid < C) bs[tid] = bo[tid];

    #pragma unroll
    for (int j = 0; j < 4; ++j) {
        int f4 = tid + (j << 8);
        int r = f4 >> 4;
        int i0 = (f4 & 15) << 2;
        int grow = rowBase + r;
        float4 xv = make_float4(0.f, 0.f, 0.f, 0.f);
        if (grow < N) {
            xv = ld4g(&acc[(size_t)grow * C + i0]);
            float dn = den[grow * H + (i0 >> 4)];
            float inv = dn > 0.f ? 1.f / dn : 0.f;   // no-edge node -> 0 (matches ref)
            xv.x *= inv; xv.y *= inv; xv.z *= inv; xv.w *= inv;
        }
        XT[i0 + 0][r] = xv.x; XT[i0 + 1][r] = xv.y;
        XT[i0 + 2][r] = xv.z; XT[i0 + 3][r] = xv.w;
    }
    __syncthreads();

    const int lane = tid & 63;
    const int wid = tid >> 6;
    const int r0 = (wid << 4) + ((lane >> 4) << 2);
    const int c0 = (lane & 15) << 2;

    float4 b = *(const float4*)&bs[c0];
    float4 a[4] = { b, b, b, b };
    for (int i = 0; i < C; ++i) {
        float4 xr = *(const float4*)&XT[i][r0];
        float4 w = *(const float4*)&WT[i][c0];
        fma4(a[0], xr.x, w);
        fma4(a[1], xr.y, w);
        fma4(a[2], xr.z, w);
        fma4(a[3], xr.w, w);
    }
    #pragma unroll
    for (int j = 0; j < 4; ++j) {
        int grow = rowBase + r0 + j;
        if (grow < N) {
            float4 cur = ld4g(&history[((size_t)grow * L + (L - 1)) * C + c0]);
            float4 o = a[j];
            o.x += cur.x; o.y += cur.y; o.z += cur.z; o.w += cur.w;
            st4g(&out[(size_t)grow * C + c0], o);
        }
    }
}

extern "C" void kernel_launch(void* const* d_in, const int* in_sizes, int n_in,
                              void* d_out, int out_size, void* d_ws, size_t ws_size,
                              hipStream_t stream)
{
    const float* history = (const float*)d_in[0];
    const int*   ei      = (const int*)d_in[1];
    const float* Wq = (const float*)d_in[2];
    const float* bq = (const float*)d_in[3];
    const float* Wk = (const float*)d_in[4];
    const float* bk = (const float*)d_in[5];
    const float* Wv = (const float*)d_in[6];
    const float* bv = (const float*)d_in[7];
    const float* Wo = (const float*)d_in[8];
    const float* bo = (const float*)d_in[9];
    const int N = in_sizes[0] / (L * C);
    const int E = in_sizes[1] / 2;

    float* ws   = (float*)d_ws;
    float* qbuf = ws;                              // N*C
    float* kbuf = qbuf + (size_t)N * C;            // N*L*C
    float* vbuf = kbuf + (size_t)N * L * C;        // N*L*C
    float* accb = vbuf + (size_t)N * L * C;        // N*C
    float* denb = accb + (size_t)N * C;            // N*H

    hipMemsetAsync(accb, 0, (size_t)(N * C + N * H) * sizeof(float), stream);

    const int nkv = (N * L + 63) / 64;
    const int nq  = (N + 63) / 64;
    qkv_kernel<<<nkv + nq, 256, 0, stream>>>(history, Wk, bk, Wv, bv, Wq, bq,
                                             kbuf, vbuf, qbuf, N, nkv);

    const int ewaves  = (E + 3) / 4;
    const int eblocks = (ewaves + 3) / 4;
    edge_kernel<<<eblocks, 256, 0, stream>>>(ei, qbuf, kbuf, vbuf, accb, denb, E);

    out_kernel<<<nq, 256, 0, stream>>>(accb, denb, history, Wo, bo, (float*)d_out, N);
}

// Round 2
// 468.786 us; speedup vs baseline: 1.7848x; 1.7848x over previous
//
#include <hip/hip_runtime.h>

#define DEV __device__ __forceinline__

constexpr int L = 3;
constexpr int C = 64;
constexpr int H = 4;
constexpr int CP = 68;   // padded LDS stride: keeps float4 16B-aligned, spreads banks

DEV float4 ld4g(const float* p) { return *reinterpret_cast<const float4*>(p); }
DEV void st4g(float* p, float4 v) { *reinterpret_cast<float4*>(p) = v; }
DEV void fma4(float4& a, float s, float4 w) {
    a.x = fmaf(s, w.x, a.x); a.y = fmaf(s, w.y, a.y);
    a.z = fmaf(s, w.z, a.z); a.w = fmaf(s, w.w, a.w);
}

// ---------------------------------------------------------------------------
// QKV projection. Blocks [0, nkvBlocks): compute k,v rows (task space N*L).
// Blocks [nkvBlocks, ...): compute q rows (task space N, source row = n*L+L-1).
// 64 rows x 64 cols per block; 4x4 register tile per lane.
// q is pre-scaled by 1/sqrt(D) = 0.25.
// ---------------------------------------------------------------------------
__global__ __launch_bounds__(256) void qkv_kernel(
    const float* __restrict__ history,
    const float* __restrict__ Wk, const float* __restrict__ bk,
    const float* __restrict__ Wv, const float* __restrict__ bv,
    const float* __restrict__ Wq, const float* __restrict__ bq,
    float* __restrict__ kout, float* __restrict__ vout, float* __restrict__ qout,
    int N, int nkvBlocks)
{
    __shared__ float XT[C][CP];
    __shared__ float W1T[C][CP];
    __shared__ float W2T[C][CP];
    __shared__ float b1s[C], b2s[C];

    const bool isKV = (int)blockIdx.x < nkvBlocks;
    const int rowBase = (isKV ? blockIdx.x : (blockIdx.x - nkvBlocks)) * 64;
    const int totalRows = isKV ? N * L : N;
    const int tid = threadIdx.x;

    #pragma unroll
    for (int j = 0; j < 16; ++j) {
        int idx = tid + (j << 8);
        int ii = idx & 63, cc = idx >> 6;   // W[c][i] -> WT[i][c]
        if (isKV) {
            W1T[ii][cc] = Wk[idx];
            W2T[ii][cc] = Wv[idx];
        } else {
            W1T[ii][cc] = Wq[idx];
        }
    }
    if (tid < C) {
        b1s[tid] = isKV ? bk[tid] : bq[tid];
        b2s[tid] = isKV ? bv[tid] : 0.f;
    }
    #pragma unroll
    for (int j = 0; j < 4; ++j) {
        int f4 = tid + (j << 8);
        int r = f4 >> 4;
        int i0 = (f4 & 15) << 2;
        int grow = rowBase + r;
        float4 xv = make_float4(0.f, 0.f, 0.f, 0.f);
        if (grow < totalRows) {
            size_t srcRow = isKV ? (size_t)grow : ((size_t)grow * L + (L - 1));
            xv = ld4g(&history[srcRow * C + i0]);
        }
        XT[i0 + 0][r] = xv.x; XT[i0 + 1][r] = xv.y;
        XT[i0 + 2][r] = xv.z; XT[i0 + 3][r] = xv.w;
    }
    __syncthreads();

    const int lane = tid & 63;
    const int wid = tid >> 6;
    const int r0 = (wid << 4) + ((lane >> 4) << 2);  // local row base
    const int c0 = (lane & 15) << 2;                 // col base

    float4 b1 = *(const float4*)&b1s[c0];
    float4 acc1[4] = { b1, b1, b1, b1 };

    if (isKV) {
        float4 b2 = *(const float4*)&b2s[c0];
        float4 acc2[4] = { b2, b2, b2, b2 };
        for (int i = 0; i < C; ++i) {
            float4 xr = *(const float4*)&XT[i][r0];
            float4 w1 = *(const float4*)&W1T[i][c0];
            float4 w2 = *(const float4*)&W2T[i][c0];
            fma4(acc1[0], xr.x, w1); fma4(acc2[0], xr.x, w2);
            fma4(acc1[1], xr.y, w1); fma4(acc2[1], xr.y, w2);
            fma4(acc1[2], xr.z, w1); fma4(acc2[2], xr.z, w2);
            fma4(acc1[3], xr.w, w1); fma4(acc2[3], xr.w, w2);
        }
        #pragma unroll
        for (int j = 0; j < 4; ++j) {
            int grow = rowBase + r0 + j;
            if (grow < totalRows) {
                st4g(&kout[(size_t)grow * C + c0], acc1[j]);
                st4g(&vout[(size_t)grow * C + c0], acc2[j]);
            }
        }
    } else {
        for (int i = 0; i < C; ++i) {
            float4 xr = *(const float4*)&XT[i][r0];
            float4 w1 = *(const float4*)&W1T[i][c0];
            fma4(acc1[0], xr.x, w1);
            fma4(acc1[1], xr.y, w1);
            fma4(acc1[2], xr.z, w1);
            fma4(acc1[3], xr.w, w1);
        }
        #pragma unroll
        for (int j = 0; j < 4; ++j) {
            int grow = rowBase + r0 + j;
            if (grow < totalRows) {
                float4 o = acc1[j];
                o.x *= 0.25f; o.y *= 0.25f; o.z *= 0.25f; o.w *= 0.25f;
                st4g(&qout[(size_t)grow * C + c0], o);
            }
        }
    }
}

// ---------------------------------------------------------------------------
// CSR build: histogram of destination (col) -> exclusive scan -> edge scatter
// ---------------------------------------------------------------------------
__global__ __launch_bounds__(256) void hist_kernel(
    const int* __restrict__ ei, int* __restrict__ counts, int E)
{
    int e = blockIdx.x * 256 + threadIdx.x;
    if (e < E) atomicAdd(&counts[ei[E + e]], 1);
}

__global__ __launch_bounds__(256) void scan_kernel(
    const int* __restrict__ counts, int* __restrict__ offs,
    int* __restrict__ cursor, int N)
{
    __shared__ int ps[256];
    const int t = threadIdx.x;
    const int chunk = (N + 255) / 256;
    const int lo = t * chunk;
    const int hi = min(N, lo + chunk);
    int s = 0;
    for (int i = lo; i < hi; ++i) s += counts[i];
    ps[t] = s;
    __syncthreads();
    for (int off = 1; off < 256; off <<= 1) {
        int vv = (t >= off) ? ps[t - off] : 0;
        __syncthreads();
        ps[t] += vv;
        __syncthreads();
    }
    int run = (t == 0) ? 0 : ps[t - 1];
    for (int i = lo; i < hi; ++i) {
        offs[i] = run;
        cursor[i] = run;
        run += counts[i];
    }
}

__global__ __launch_bounds__(256) void scatter_kernel(
    const int* __restrict__ ei, int* __restrict__ cursor,
    int* __restrict__ eids, int E)
{
    int e = blockIdx.x * 256 + threadIdx.x;
    if (e < E) {
        int c = ei[E + e];
        int p = atomicAdd(&cursor[c], 1);
        eids[p] = e;
    }
}

// ---------------------------------------------------------------------------
// Atomic-free gather: one wave per destination node. 16 lanes/edge covering
// C=64 channels, 4 edges in flight (sub-groups). Token softmax over L=3 per
// head; edge normalization factored out (softmax shift-invariance, no seg_max
// needed since |scores| <~ 8):
//   acc[n] = (sum_e msg_e * ee_e) / (sum_e ee_e),  ee = exp(max_t score)
// Output written once per node, normalized — no atomics, no den buffer.
// ---------------------------------------------------------------------------
__global__ __launch_bounds__(256) void gather_kernel(
    const int* __restrict__ ei,
    const int* __restrict__ offs, const int* __restrict__ counts,
    const int* __restrict__ eids,
    const float* __restrict__ q, const float* __restrict__ k,
    const float* __restrict__ v,
    float* __restrict__ acc, int N, int E)
{
    const int wave = blockIdx.x * 4 + (threadIdx.x >> 6);
    if (wave >= N) return;
    const int n = wave;
    const int lane = threadIdx.x & 63;
    const int sub = lane >> 4;    // edge slot within wave
    const int ld = lane & 15;     // lane within edge: head = ld>>2
    const int c0 = ld << 2;

    const int start = offs[n];
    const int cnt = counts[n];

    const float4 qv = ld4g(&q[(size_t)n * C + c0]);   // pre-scaled by 0.25
    float4 macc = make_float4(0.f, 0.f, 0.f, 0.f);
    float dsum = 0.f;

    for (int i = sub; i < cnt; i += 4) {
        const int e = eids[start + i];
        const int row = ei[e];   // src node
        const float* kb = &k[(size_t)row * (L * C)];
        const float* vb = &v[(size_t)row * (L * C)];
        float4 k0 = ld4g(kb + c0), k1 = ld4g(kb + C + c0), k2 = ld4g(kb + 2 * C + c0);

        float s0 = qv.x * k0.x + qv.y * k0.y + qv.z * k0.z + qv.w * k0.w;
        float s1 = qv.x * k1.x + qv.y * k1.y + qv.z * k1.z + qv.w * k1.w;
        float s2 = qv.x * k2.x + qv.y * k2.y + qv.z * k2.z + qv.w * k2.w;
        // reduce over the 4 lanes of this head (partners share sub => same mask)
        s0 += __shfl_xor(s0, 1); s0 += __shfl_xor(s0, 2);
        s1 += __shfl_xor(s1, 1); s1 += __shfl_xor(s1, 2);
        s2 += __shfl_xor(s2, 1); s2 += __shfl_xor(s2, 2);

        float e0 = __expf(s0), e1 = __expf(s1), e2 = __expf(s2);
        float ee = fmaxf(fmaxf(e0, e1), e2);        // = exp(max token score)
        float sc = ee / (e0 + e1 + e2);
        float w0 = e0 * sc, w1 = e1 * sc, w2 = e2 * sc;

        float4 v0 = ld4g(vb + c0), v1 = ld4g(vb + C + c0), v2 = ld4g(vb + 2 * C + c0);
        macc.x += w0 * v0.x + w1 * v1.x + w2 * v2.x;
        macc.y += w0 * v0.y + w1 * v1.y + w2 * v2.y;
        macc.z += w0 * v0.z + w1 * v1.z + w2 * v2.z;
        macc.w += w0 * v0.w + w1 * v1.w + w2 * v2.w;
        dsum += ee;
    }

    // reduce the 4 edge slots (lanes differing in bits 4,5)
    macc.x += __shfl_xor(macc.x, 16); macc.x += __shfl_xor(macc.x, 32);
    macc.y += __shfl_xor(macc.y, 16); macc.y += __shfl_xor(macc.y, 32);
    macc.z += __shfl_xor(macc.z, 16); macc.z += __shfl_xor(macc.z, 32);
    macc.w += __shfl_xor(macc.w, 16); macc.w += __shfl_xor(macc.w, 32);
    dsum   += __shfl_xor(dsum, 16);   dsum   += __shfl_xor(dsum, 32);

    if (sub == 0) {
        float inv = dsum > 0.f ? 1.f / dsum : 0.f;   // cnt==0 -> zeros (matches ref)
        float4 o;
        o.x = macc.x * inv; o.y = macc.y * inv;
        o.z = macc.z * inv; o.w = macc.w * inv;
        st4g(&acc[(size_t)n * C + c0], o);
    }
}

// ---------------------------------------------------------------------------
// Output projection: out = acc @ Wo.T + bo + current   (acc pre-normalized)
// ---------------------------------------------------------------------------
__global__ __launch_bounds__(256) void out_kernel(
    const float* __restrict__ acc,
    const float* __restrict__ history,
    const float* __restrict__ Wo, const float* __restrict__ bo,
    float* __restrict__ out, int N)
{
    __shared__ float XT[C][CP];
    __shared__ float WT[C][CP];
    __shared__ float bs[C];
    const int tid = threadIdx.x;
    const int rowBase = blockIdx.x * 64;

    #pragma unroll
    for (int j = 0; j < 16; ++j) {
        int idx = tid + (j << 8);
        WT[idx & 63][idx >> 6] = Wo[idx];
    }
    if (tid < C) bs[tid] = bo[tid];

    #pragma unroll
    for (int j = 0; j < 4; ++j) {
        int f4 = tid + (j << 8);
        int r = f4 >> 4;
        int i0 = (f4 & 15) << 2;
        int grow = rowBase + r;
        float4 xv = make_float4(0.f, 0.f, 0.f, 0.f);
        if (grow < N) xv = ld4g(&acc[(size_t)grow * C + i0]);
        XT[i0 + 0][r] = xv.x; XT[i0 + 1][r] = xv.y;
        XT[i0 + 2][r] = xv.z; XT[i0 + 3][r] = xv.w;
    }
    __syncthreads();

    const int lane = tid & 63;
    const int wid = tid >> 6;
    const int r0 = (wid << 4) + ((lane >> 4) << 2);
    const int c0 = (lane & 15) << 2;

    float4 b = *(const float4*)&bs[c0];
    float4 a[4] = { b, b, b, b };
    for (int i = 0; i < C; ++i) {
        float4 xr = *(const float4*)&XT[i][r0];
        float4 w = *(const float4*)&WT[i][c0];
        fma4(a[0], xr.x, w);
        fma4(a[1], xr.y, w);
        fma4(a[2], xr.z, w);
        fma4(a[3], xr.w, w);
    }
    #pragma unroll
    for (int j = 0; j < 4; ++j) {
        int grow = rowBase + r0 + j;
        if (grow < N) {
            float4 cur = ld4g(&history[((size_t)grow * L + (L - 1)) * C + c0]);
            float4 o = a[j];
            o.x += cur.x; o.y += cur.y; o.z += cur.z; o.w += cur.w;
            st4g(&out[(size_t)grow * C + c0], o);
        }
    }
}

extern "C" void kernel_launch(void* const* d_in, const int* in_sizes, int n_in,
                              void* d_out, int out_size, void* d_ws, size_t ws_size,
                              hipStream_t stream)
{
    const float* history = (const float*)d_in[0];
    const int*   ei      = (const int*)d_in[1];
    const float* Wq = (const float*)d_in[2];
    const float* bq = (const float*)d_in[3];
    const float* Wk = (const float*)d_in[4];
    const float* bk = (const float*)d_in[5];
    const float* Wv = (const float*)d_in[6];
    const float* bv = (const float*)d_in[7];
    const float* Wo = (const float*)d_in[8];
    const float* bo = (const float*)d_in[9];
    const int N = in_sizes[0] / (L * C);
    const int E = in_sizes[1] / 2;

    float* ws   = (float*)d_ws;
    float* qbuf = ws;                              // N*C
    float* kbuf = qbuf + (size_t)N * C;            // N*L*C
    float* vbuf = kbuf + (size_t)N * L * C;        // N*L*C
    float* accb = vbuf + (size_t)N * L * C;        // N*C
    int*   counts = (int*)(accb + (size_t)N * C);  // N
    int*   offs   = counts + N;                    // N
    int*   cursor = offs + N;                      // N
    int*   eids   = cursor + N;                    // E

    hipMemsetAsync(counts, 0, (size_t)N * sizeof(int), stream);

    const int nkv = (N * L + 63) / 64;
    const int nq  = (N + 63) / 64;
    qkv_kernel<<<nkv + nq, 256, 0, stream>>>(history, Wk, bk, Wv, bv, Wq, bq,
                                             kbuf, vbuf, qbuf, N, nkv);

    const int eb = (E + 255) / 256;
    hist_kernel<<<eb, 256, 0, stream>>>(ei, counts, E);
    scan_kernel<<<1, 256, 0, stream>>>(counts, offs, cursor, N);
    scatter_kernel<<<eb, 256, 0, stream>>>(ei, cursor, eids, E);

    gather_kernel<<<(N + 3) / 4, 256, 0, stream>>>(ei, offs, counts, eids,
                                                   qbuf, kbuf, vbuf, accb, N, E);

    out_kernel<<<nq, 256, 0, stream>>>(accb, history, Wo, bo, (float*)d_out, N);
}

// Round 3
// 251.319 us; speedup vs baseline: 3.3292x; 1.8653x over previous
//
#include <hip/hip_runtime.h>

#define DEV __device__ __forceinline__

constexpr int L = 3;
constexpr int C = 64;
constexpr int H = 4;
constexpr int CP = 68;   // padded LDS stride for fp32 GEMM tiles

typedef unsigned short ushort8v __attribute__((ext_vector_type(8)));
typedef unsigned short ushort4v __attribute__((ext_vector_type(4)));

DEV float4 ld4g(const float* p) { return *reinterpret_cast<const float4*>(p); }
DEV void st4g(float* p, float4 v) { *reinterpret_cast<float4*>(p) = v; }
DEV void fma4(float4& a, float s, float4 w) {
    a.x = fmaf(s, w.x, a.x); a.y = fmaf(s, w.y, a.y);
    a.z = fmaf(s, w.z, a.z); a.w = fmaf(s, w.w, a.w);
}
DEV float b2f(unsigned short u) {
    union { float f; unsigned int i; } x; x.i = ((unsigned int)u) << 16; return x.f;
}
DEV unsigned short f2b(float f) {   // RNE, values are finite/normal here
    unsigned int u = __float_as_uint(f);
    return (unsigned short)((u + 0x7FFFu + ((u >> 16) & 1u)) >> 16);
}
DEV float dot8(float4 a, float4 b, ushort8v k) {
    return a.x*b2f(k[0]) + a.y*b2f(k[1]) + a.z*b2f(k[2]) + a.w*b2f(k[3])
         + b.x*b2f(k[4]) + b.y*b2f(k[5]) + b.z*b2f(k[6]) + b.w*b2f(k[7]);
}
DEV void acc8(float4& A, float4& B, float w, ushort8v v) {
    A.x = fmaf(w, b2f(v[0]), A.x); A.y = fmaf(w, b2f(v[1]), A.y);
    A.z = fmaf(w, b2f(v[2]), A.z); A.w = fmaf(w, b2f(v[3]), A.w);
    B.x = fmaf(w, b2f(v[4]), B.x); B.y = fmaf(w, b2f(v[5]), B.y);
    B.z = fmaf(w, b2f(v[6]), B.z); B.w = fmaf(w, b2f(v[7]), B.w);
}

// ---------------------------------------------------------------------------
// QKV projection. KV blocks write bf16 packed per node: kv[node][t][k:64bf16][v:64bf16]
// Q blocks write fp32, pre-scaled by 1/sqrt(D)=0.25.
// ---------------------------------------------------------------------------
__global__ __launch_bounds__(256) void qkv_kernel(
    const float* __restrict__ history,
    const float* __restrict__ Wk, const float* __restrict__ bk,
    const float* __restrict__ Wv, const float* __restrict__ bv,
    const float* __restrict__ Wq, const float* __restrict__ bq,
    unsigned short* __restrict__ kvout, float* __restrict__ qout,
    int N, int nkvBlocks)
{
    __shared__ float XT[C][CP];
    __shared__ float W1T[C][CP];
    __shared__ float W2T[C][CP];
    __shared__ float b1s[C], b2s[C];

    const bool isKV = (int)blockIdx.x < nkvBlocks;
    const int rowBase = (isKV ? blockIdx.x : (blockIdx.x - nkvBlocks)) * 64;
    const int totalRows = isKV ? N * L : N;
    const int tid = threadIdx.x;

    #pragma unroll
    for (int j = 0; j < 16; ++j) {
        int idx = tid + (j << 8);
        int ii = idx & 63, cc = idx >> 6;
        if (isKV) {
            W1T[ii][cc] = Wk[idx];
            W2T[ii][cc] = Wv[idx];
        } else {
            W1T[ii][cc] = Wq[idx];
        }
    }
    if (tid < C) {
        b1s[tid] = isKV ? bk[tid] : bq[tid];
        b2s[tid] = isKV ? bv[tid] : 0.f;
    }
    #pragma unroll
    for (int j = 0; j < 4; ++j) {
        int f4 = tid + (j << 8);
        int r = f4 >> 4;
        int i0 = (f4 & 15) << 2;
        int grow = rowBase + r;
        float4 xv = make_float4(0.f, 0.f, 0.f, 0.f);
        if (grow < totalRows) {
            size_t srcRow = isKV ? (size_t)grow : ((size_t)grow * L + (L - 1));
            xv = ld4g(&history[srcRow * C + i0]);
        }
        XT[i0 + 0][r] = xv.x; XT[i0 + 1][r] = xv.y;
        XT[i0 + 2][r] = xv.z; XT[i0 + 3][r] = xv.w;
    }
    __syncthreads();

    const int lane = tid & 63;
    const int wid = tid >> 6;
    const int r0 = (wid << 4) + ((lane >> 4) << 2);
    const int c0 = (lane & 15) << 2;

    float4 b1 = *(const float4*)&b1s[c0];
    float4 acc1[4] = { b1, b1, b1, b1 };

    if (isKV) {
        float4 b2 = *(const float4*)&b2s[c0];
        float4 acc2[4] = { b2, b2, b2, b2 };
        for (int i = 0; i < C; ++i) {
            float4 xr = *(const float4*)&XT[i][r0];
            float4 w1 = *(const float4*)&W1T[i][c0];
            float4 w2 = *(const float4*)&W2T[i][c0];
            fma4(acc1[0], xr.x, w1); fma4(acc2[0], xr.x, w2);
            fma4(acc1[1], xr.y, w1); fma4(acc2[1], xr.y, w2);
            fma4(acc1[2], xr.z, w1); fma4(acc2[2], xr.z, w2);
            fma4(acc1[3], xr.w, w1); fma4(acc2[3], xr.w, w2);
        }
        #pragma unroll
        for (int j = 0; j < 4; ++j) {
            int grow = rowBase + r0 + j;
            if (grow < totalRows) {
                int node = grow / 3;
                int t = grow - node * 3;
                unsigned short* dst = kvout + (size_t)node * (L * 2 * C) + t * (2 * C) + c0;
                ushort4v kp, vp;
                kp[0] = f2b(acc1[j].x); kp[1] = f2b(acc1[j].y);
                kp[2] = f2b(acc1[j].z); kp[3] = f2b(acc1[j].w);
                vp[0] = f2b(acc2[j].x); vp[1] = f2b(acc2[j].y);
                vp[2] = f2b(acc2[j].z); vp[3] = f2b(acc2[j].w);
                *(ushort4v*)dst = kp;
                *(ushort4v*)(dst + C) = vp;
            }
        }
    } else {
        for (int i = 0; i < C; ++i) {
            float4 xr = *(const float4*)&XT[i][r0];
            float4 w1 = *(const float4*)&W1T[i][c0];
            fma4(acc1[0], xr.x, w1);
            fma4(acc1[1], xr.y, w1);
            fma4(acc1[2], xr.z, w1);
            fma4(acc1[3], xr.w, w1);
        }
        #pragma unroll
        for (int j = 0; j < 4; ++j) {
            int grow = rowBase + r0 + j;
            if (grow < totalRows) {
                float4 o = acc1[j];
                o.x *= 0.25f; o.y *= 0.25f; o.z *= 0.25f; o.w *= 0.25f;
                st4g(&qout[(size_t)grow * C + c0], o);
            }
        }
    }
}

// ---------------------------------------------------------------------------
// CSR build: histogram -> two-level exclusive scan -> scatter src ids
// ---------------------------------------------------------------------------
__global__ __launch_bounds__(256) void hist_kernel(
    const int* __restrict__ ei, int* __restrict__ counts, int E)
{
    int e = blockIdx.x * 256 + threadIdx.x;
    if (e < E) atomicAdd(&counts[ei[E + e]], 1);
}

__global__ __launch_bounds__(256) void scan1_kernel(
    const int* __restrict__ counts, int* __restrict__ offs,
    int* __restrict__ blockSums, int N)
{
    __shared__ int s[256];
    const int t = threadIdx.x;
    const int gid = blockIdx.x * 256 + t;
    int v = (gid < N) ? counts[gid] : 0;
    s[t] = v;
    __syncthreads();
    for (int o = 1; o < 256; o <<= 1) {
        int x = (t >= o) ? s[t - o] : 0;
        __syncthreads();
        s[t] += x;
        __syncthreads();
    }
    if (gid < N) offs[gid] = s[t] - v;        // exclusive, local
    if (t == 255) blockSums[blockIdx.x] = s[255];
}

__global__ __launch_bounds__(256) void scan2_kernel(
    const int* __restrict__ blockSums, int* __restrict__ blockBase, int B)
{
    __shared__ int s[256];
    const int t = threadIdx.x;
    int v = (t < B) ? blockSums[t] : 0;
    s[t] = v;
    __syncthreads();
    for (int o = 1; o < 256; o <<= 1) {
        int x = (t >= o) ? s[t - o] : 0;
        __syncthreads();
        s[t] += x;
        __syncthreads();
    }
    blockBase[t] = s[t] - v;                  // exclusive
}

__global__ __launch_bounds__(256) void scan3_kernel(
    int* __restrict__ offs, int* __restrict__ cursor,
    const int* __restrict__ blockBase, int N)
{
    int gid = blockIdx.x * 256 + threadIdx.x;
    if (gid < N) {
        int o = offs[gid] + blockBase[blockIdx.x];
        offs[gid] = o;
        cursor[gid] = o;
    }
}

__global__ __launch_bounds__(256) void scatter_kernel(
    const int* __restrict__ ei, int* __restrict__ cursor,
    int* __restrict__ srcs, int E)
{
    int e = blockIdx.x * 256 + threadIdx.x;
    if (e < E) {
        int c = ei[E + e];
        int r = ei[e];
        int p = atomicAdd(&cursor[c], 1);
        srcs[p] = r;
    }
}

// ---------------------------------------------------------------------------
// Atomic-free gather, bf16 kv. One wave per dst node; 8 lanes/edge (8 channels
// each), 8 edge slots in flight. Token softmax over L=3 per head (head = 2
// lanes -> one shfl_xor(1)); edge softmax factored out of the scatter:
//   acc[n] = (sum_e msg_e * ee_e) / (sum_e ee_e),  ee = exp(max_t score)
// ---------------------------------------------------------------------------
__global__ __launch_bounds__(256) void gather_kernel(
    const int* __restrict__ srcs,
    const int* __restrict__ offs, const int* __restrict__ counts,
    const float* __restrict__ q, const unsigned short* __restrict__ kv,
    float* __restrict__ acc, int N)
{
    const int wave = blockIdx.x * 4 + (threadIdx.x >> 6);
    if (wave >= N) return;
    const int n = wave;
    const int lane = threadIdx.x & 63;
    const int sub = lane >> 3;    // edge slot 0..7
    const int ld = lane & 7;      // lane within edge; head = ld>>1
    const int c0 = ld << 3;       // channel base (8 channels per lane)

    const int start = offs[n];
    const int cnt = counts[n];

    const float4 qa = ld4g(&q[(size_t)n * C + c0]);       // pre-scaled by 0.25
    const float4 qb = ld4g(&q[(size_t)n * C + c0 + 4]);
    float4 ma = make_float4(0.f, 0.f, 0.f, 0.f);
    float4 mb = make_float4(0.f, 0.f, 0.f, 0.f);
    float dsum = 0.f;

    for (int i = sub; i < cnt; i += 8) {
        const int src = srcs[start + i];
        const unsigned short* kb = kv + (size_t)src * (L * 2 * C) + c0;
        ushort8v k0 = *(const ushort8v*)(kb);
        ushort8v k1 = *(const ushort8v*)(kb + 2 * C);
        ushort8v k2 = *(const ushort8v*)(kb + 4 * C);

        float s0 = dot8(qa, qb, k0);
        float s1 = dot8(qa, qb, k1);
        float s2 = dot8(qa, qb, k2);
        s0 += __shfl_xor(s0, 1);   // head spans 2 lanes
        s1 += __shfl_xor(s1, 1);
        s2 += __shfl_xor(s2, 1);

        float e0 = __expf(s0), e1 = __expf(s1), e2 = __expf(s2);
        float ee = fmaxf(fmaxf(e0, e1), e2);      // = exp(max token score)
        float sc = ee / (e0 + e1 + e2);
        float w0 = e0 * sc, w1 = e1 * sc, w2 = e2 * sc;

        ushort8v v0 = *(const ushort8v*)(kb + C);
        ushort8v v1 = *(const ushort8v*)(kb + 3 * C);
        ushort8v v2 = *(const ushort8v*)(kb + 5 * C);
        acc8(ma, mb, w0, v0);
        acc8(ma, mb, w1, v1);
        acc8(ma, mb, w2, v2);
        dsum += ee;
    }

    // reduce the 8 edge slots (lane bits 3,4,5)
    #pragma unroll
    for (int m = 8; m <= 32; m <<= 1) {
        ma.x += __shfl_xor(ma.x, m); ma.y += __shfl_xor(ma.y, m);
        ma.z += __shfl_xor(ma.z, m); ma.w += __shfl_xor(ma.w, m);
        mb.x += __shfl_xor(mb.x, m); mb.y += __shfl_xor(mb.y, m);
        mb.z += __shfl_xor(mb.z, m); mb.w += __shfl_xor(mb.w, m);
        dsum += __shfl_xor(dsum, m);
    }

    if (sub == 0) {
        float inv = dsum > 0.f ? 1.f / dsum : 0.f;   // cnt==0 -> zeros (matches ref)
        float4 oa, ob;
        oa.x = ma.x * inv; oa.y = ma.y * inv; oa.z = ma.z * inv; oa.w = ma.w * inv;
        ob.x = mb.x * inv; ob.y = mb.y * inv; ob.z = mb.z * inv; ob.w = mb.w * inv;
        st4g(&acc[(size_t)n * C + c0], oa);
        st4g(&acc[(size_t)n * C + c0 + 4], ob);
    }
}

// ---------------------------------------------------------------------------
// Output projection: out = acc @ Wo.T + bo + current   (acc pre-normalized)
// ---------------------------------------------------------------------------
__global__ __launch_bounds__(256) void out_kernel(
    const float* __restrict__ acc,
    const float* __restrict__ history,
    const float* __restrict__ Wo, const float* __restrict__ bo,
    float* __restrict__ out, int N)
{
    __shared__ float XT[C][CP];
    __shared__ float WT[C][CP];
    __shared__ float bs[C];
    const int tid = threadIdx.x;
    const int rowBase = blockIdx.x * 64;

    #pragma unroll
    for (int j = 0; j < 16; ++j) {
        int idx = tid + (j << 8);
        WT[idx & 63][idx >> 6] = Wo[idx];
    }
    if (tid < C) bs[tid] = bo[tid];

    #pragma unroll
    for (int j = 0; j < 4; ++j) {
        int f4 = tid + (j << 8);
        int r = f4 >> 4;
        int i0 = (f4 & 15) << 2;
        int grow = rowBase + r;
        float4 xv = make_float4(0.f, 0.f, 0.f, 0.f);
        if (grow < N) xv = ld4g(&acc[(size_t)grow * C + i0]);
        XT[i0 + 0][r] = xv.x; XT[i0 + 1][r] = xv.y;
        XT[i0 + 2][r] = xv.z; XT[i0 + 3][r] = xv.w;
    }
    __syncthreads();

    const int lane = tid & 63;
    const int wid = tid >> 6;
    const int r0 = (wid << 4) + ((lane >> 4) << 2);
    const int c0 = (lane & 15) << 2;

    float4 b = *(const float4*)&bs[c0];
    float4 a[4] = { b, b, b, b };
    for (int i = 0; i < C; ++i) {
        float4 xr = *(const float4*)&XT[i][r0];
        float4 w = *(const float4*)&WT[i][c0];
        fma4(a[0], xr.x, w);
        fma4(a[1], xr.y, w);
        fma4(a[2], xr.z, w);
        fma4(a[3], xr.w, w);
    }
    #pragma unroll
    for (int j = 0; j < 4; ++j) {
        int grow = rowBase + r0 + j;
        if (grow < N) {
            float4 cur = ld4g(&history[((size_t)grow * L + (L - 1)) * C + c0]);
            float4 o = a[j];
            o.x += cur.x; o.y += cur.y; o.z += cur.z; o.w += cur.w;
            st4g(&out[(size_t)grow * C + c0], o);
        }
    }
}

extern "C" void kernel_launch(void* const* d_in, const int* in_sizes, int n_in,
                              void* d_out, int out_size, void* d_ws, size_t ws_size,
                              hipStream_t stream)
{
    const float* history = (const float*)d_in[0];
    const int*   ei      = (const int*)d_in[1];
    const float* Wq = (const float*)d_in[2];
    const float* bq = (const float*)d_in[3];
    const float* Wk = (const float*)d_in[4];
    const float* bk = (const float*)d_in[5];
    const float* Wv = (const float*)d_in[6];
    const float* bv = (const float*)d_in[7];
    const float* Wo = (const float*)d_in[8];
    const float* bo = (const float*)d_in[9];
    const int N = in_sizes[0] / (L * C);
    const int E = in_sizes[1] / 2;

    float* ws   = (float*)d_ws;
    float* qbuf = ws;                                   // N*C fp32
    float* accb = qbuf + (size_t)N * C;                 // N*C fp32
    unsigned short* kvbuf = (unsigned short*)(accb + (size_t)N * C);  // N*L*2C bf16
    int* counts    = (int*)(kvbuf + (size_t)N * L * 2 * C);           // N
    int* offs      = counts + N;                        // N
    int* cursor    = offs + N;                          // N
    int* srcs      = cursor + N;                        // E
    int* blockSums = srcs + E;                          // 256
    int* blockBase = blockSums + 256;                   // 256

    hipMemsetAsync(counts, 0, (size_t)N * sizeof(int), stream);

    const int nkv = (N * L + 63) / 64;
    const int nq  = (N + 63) / 64;
    qkv_kernel<<<nkv + nq, 256, 0, stream>>>(history, Wk, bk, Wv, bv, Wq, bq,
                                             kvbuf, qbuf, N, nkv);

    const int eb = (E + 255) / 256;
    const int sb = (N + 255) / 256;   // 196 blocks <= 256
    hist_kernel<<<eb, 256, 0, stream>>>(ei, counts, E);
    scan1_kernel<<<sb, 256, 0, stream>>>(counts, offs, blockSums, N);
    scan2_kernel<<<1, 256, 0, stream>>>(blockSums, blockBase, sb);
    scan3_kernel<<<sb, 256, 0, stream>>>(offs, cursor, blockBase, N);
    scatter_kernel<<<eb, 256, 0, stream>>>(ei, cursor, srcs, E);

    gather_kernel<<<(N + 3) / 4, 256, 0, stream>>>(srcs, offs, counts,
                                                   qbuf, kvbuf, accb, N);

    out_kernel<<<nq, 256, 0, stream>>>(accb, history, Wo, bo, (float*)d_out, N);
}

// Round 4
// 229.298 us; speedup vs baseline: 3.6489x; 1.0960x over previous
//
#include <hip/hip_runtime.h>

#define DEV __device__ __forceinline__

constexpr int L = 3;
constexpr int C = 64;
constexpr int H = 4;
constexpr int CP = 68;   // padded LDS stride for fp32 GEMM tiles

typedef unsigned short ushort8v __attribute__((ext_vector_type(8)));
typedef unsigned short ushort4v __attribute__((ext_vector_type(4)));

DEV float4 ld4g(const float* p) { return *reinterpret_cast<const float4*>(p); }
DEV void st4g(float* p, float4 v) { *reinterpret_cast<float4*>(p) = v; }
DEV void fma4(float4& a, float s, float4 w) {
    a.x = fmaf(s, w.x, a.x); a.y = fmaf(s, w.y, a.y);
    a.z = fmaf(s, w.z, a.z); a.w = fmaf(s, w.w, a.w);
}
DEV float b2f(unsigned short u) {
    union { float f; unsigned int i; } x; x.i = ((unsigned int)u) << 16; return x.f;
}
DEV unsigned short f2b(float f) {   // RNE, values finite/normal here
    unsigned int u = __float_as_uint(f);
    return (unsigned short)((u + 0x7FFFu + ((u >> 16) & 1u)) >> 16);
}
DEV float dot8(float4 a, float4 b, ushort8v k) {
    return a.x*b2f(k[0]) + a.y*b2f(k[1]) + a.z*b2f(k[2]) + a.w*b2f(k[3])
         + b.x*b2f(k[4]) + b.y*b2f(k[5]) + b.z*b2f(k[6]) + b.w*b2f(k[7]);
}
DEV void acc8(float4& A, float4& B, float w, ushort8v v) {
    A.x = fmaf(w, b2f(v[0]), A.x); A.y = fmaf(w, b2f(v[1]), A.y);
    A.z = fmaf(w, b2f(v[2]), A.z); A.w = fmaf(w, b2f(v[3]), A.w);
    B.x = fmaf(w, b2f(v[4]), B.x); B.y = fmaf(w, b2f(v[5]), B.y);
    B.z = fmaf(w, b2f(v[6]), B.z); B.w = fmaf(w, b2f(v[7]), B.w);
}

// ---------------------------------------------------------------------------
// QKV projection + fused dst-histogram (one edge per thread, atomics hide
// under the GEMM). KV blocks write bf16 packed per node:
// kv[node][t][k:64bf16][v:64bf16]. Q blocks write fp32 pre-scaled by 0.25.
// ---------------------------------------------------------------------------
__global__ __launch_bounds__(256) void qkv_kernel(
    const float* __restrict__ history,
    const float* __restrict__ Wk, const float* __restrict__ bk,
    const float* __restrict__ Wv, const float* __restrict__ bv,
    const float* __restrict__ Wq, const float* __restrict__ bq,
    unsigned short* __restrict__ kvout, float* __restrict__ qout,
    const int* __restrict__ ei, int* __restrict__ counts,
    int N, int E, int nkvBlocks)
{
    __shared__ float XT[C][CP];
    __shared__ float W1T[C][CP];
    __shared__ float W2T[C][CP];
    __shared__ float b1s[C], b2s[C];

    // fused histogram: one edge per global thread
    {
        int gid = blockIdx.x * 256 + threadIdx.x;
        if (gid < E) atomicAdd(&counts[ei[E + gid]], 1);
    }

    const bool isKV = (int)blockIdx.x < nkvBlocks;
    const int rowBase = (isKV ? blockIdx.x : (blockIdx.x - nkvBlocks)) * 64;
    const int totalRows = isKV ? N * L : N;
    const int tid = threadIdx.x;

    #pragma unroll
    for (int j = 0; j < 16; ++j) {
        int idx = tid + (j << 8);
        int ii = idx & 63, cc = idx >> 6;
        if (isKV) {
            W1T[ii][cc] = Wk[idx];
            W2T[ii][cc] = Wv[idx];
        } else {
            W1T[ii][cc] = Wq[idx];
        }
    }
    if (tid < C) {
        b1s[tid] = isKV ? bk[tid] : bq[tid];
        b2s[tid] = isKV ? bv[tid] : 0.f;
    }
    #pragma unroll
    for (int j = 0; j < 4; ++j) {
        int f4 = tid + (j << 8);
        int r = f4 >> 4;
        int i0 = (f4 & 15) << 2;
        int grow = rowBase + r;
        float4 xv = make_float4(0.f, 0.f, 0.f, 0.f);
        if (grow < totalRows) {
            size_t srcRow = isKV ? (size_t)grow : ((size_t)grow * L + (L - 1));
            xv = ld4g(&history[srcRow * C + i0]);
        }
        XT[i0 + 0][r] = xv.x; XT[i0 + 1][r] = xv.y;
        XT[i0 + 2][r] = xv.z; XT[i0 + 3][r] = xv.w;
    }
    __syncthreads();

    const int lane = tid & 63;
    const int wid = tid >> 6;
    const int r0 = (wid << 4) + ((lane >> 4) << 2);
    const int c0 = (lane & 15) << 2;

    float4 b1 = *(const float4*)&b1s[c0];
    float4 acc1[4] = { b1, b1, b1, b1 };

    if (isKV) {
        float4 b2 = *(const float4*)&b2s[c0];
        float4 acc2[4] = { b2, b2, b2, b2 };
        for (int i = 0; i < C; ++i) {
            float4 xr = *(const float4*)&XT[i][r0];
            float4 w1 = *(const float4*)&W1T[i][c0];
            float4 w2 = *(const float4*)&W2T[i][c0];
            fma4(acc1[0], xr.x, w1); fma4(acc2[0], xr.x, w2);
            fma4(acc1[1], xr.y, w1); fma4(acc2[1], xr.y, w2);
            fma4(acc1[2], xr.z, w1); fma4(acc2[2], xr.z, w2);
            fma4(acc1[3], xr.w, w1); fma4(acc2[3], xr.w, w2);
        }
        #pragma unroll
        for (int j = 0; j < 4; ++j) {
            int grow = rowBase + r0 + j;
            if (grow < totalRows) {
                int node = grow / 3;
                int t = grow - node * 3;
                unsigned short* dst = kvout + (size_t)node * (L * 2 * C) + t * (2 * C) + c0;
                ushort4v kp, vp;
                kp[0] = f2b(acc1[j].x); kp[1] = f2b(acc1[j].y);
                kp[2] = f2b(acc1[j].z); kp[3] = f2b(acc1[j].w);
                vp[0] = f2b(acc2[j].x); vp[1] = f2b(acc2[j].y);
                vp[2] = f2b(acc2[j].z); vp[3] = f2b(acc2[j].w);
                *(ushort4v*)dst = kp;
                *(ushort4v*)(dst + C) = vp;
            }
        }
    } else {
        for (int i = 0; i < C; ++i) {
            float4 xr = *(const float4*)&XT[i][r0];
            float4 w1 = *(const float4*)&W1T[i][c0];
            fma4(acc1[0], xr.x, w1);
            fma4(acc1[1], xr.y, w1);
            fma4(acc1[2], xr.z, w1);
            fma4(acc1[3], xr.w, w1);
        }
        #pragma unroll
        for (int j = 0; j < 4; ++j) {
            int grow = rowBase + r0 + j;
            if (grow < totalRows) {
                float4 o = acc1[j];
                o.x *= 0.25f; o.y *= 0.25f; o.z *= 0.25f; o.w *= 0.25f;
                st4g(&qout[(size_t)grow * C + c0], o);
            }
        }
    }
}

// ---------------------------------------------------------------------------
// Two-level scan (local offsets + per-256-block bases). Consumers fold the
// base in, so no third pass is needed.
// ---------------------------------------------------------------------------
__global__ __launch_bounds__(256) void scan1_kernel(
    const int* __restrict__ counts, int* __restrict__ offs,
    int* __restrict__ cursor, int* __restrict__ blockSums, int N)
{
    __shared__ int s[256];
    const int t = threadIdx.x;
    const int gid = blockIdx.x * 256 + t;
    int v = (gid < N) ? counts[gid] : 0;
    s[t] = v;
    __syncthreads();
    for (int o = 1; o < 256; o <<= 1) {
        int x = (t >= o) ? s[t - o] : 0;
        __syncthreads();
        s[t] += x;
        __syncthreads();
    }
    if (gid < N) {
        int loc = s[t] - v;        // exclusive, local to this 256-chunk
        offs[gid] = loc;
        cursor[gid] = loc;
    }
    if (t == 255) blockSums[blockIdx.x] = s[255];
}

__global__ __launch_bounds__(256) void scan2_kernel(
    const int* __restrict__ blockSums, int* __restrict__ blockBase, int B)
{
    __shared__ int s[256];
    const int t = threadIdx.x;
    int v = (t < B) ? blockSums[t] : 0;
    s[t] = v;
    __syncthreads();
    for (int o = 1; o < 256; o <<= 1) {
        int x = (t >= o) ? s[t - o] : 0;
        __syncthreads();
        s[t] += x;
        __syncthreads();
    }
    blockBase[t] = s[t] - v;                  // exclusive
}

__global__ __launch_bounds__(256) void scatter_kernel(
    const int* __restrict__ ei, int* __restrict__ cursor,
    const int* __restrict__ blockBase, int* __restrict__ srcs, int E)
{
    int e = blockIdx.x * 256 + threadIdx.x;
    if (e < E) {
        int c = ei[E + e];
        int r = ei[e];
        int p = atomicAdd(&cursor[c], 1) + blockBase[c >> 8];
        srcs[p] = r;
    }
}

// ---------------------------------------------------------------------------
// Atomic-free gather, bf16 kv, unroll x2: one wave per dst node; 8 lanes/edge
// (8 channels each), 8 edge slots x 2 edges in flight = 16 edges/iteration.
// Token softmax over L=3 per head (head = 2 lanes -> one shfl_xor(1)); edge
// softmax factored out: acc[n] = (sum msg_e*ee_e)/(sum ee_e), ee=exp(max_t s).
// ---------------------------------------------------------------------------
__global__ __launch_bounds__(256) void gather_kernel(
    const int* __restrict__ srcs,
    const int* __restrict__ offs, const int* __restrict__ counts,
    const int* __restrict__ blockBase,
    const float* __restrict__ q, const unsigned short* __restrict__ kv,
    float* __restrict__ acc, int N)
{
    const int wave = blockIdx.x * 4 + (threadIdx.x >> 6);
    if (wave >= N) return;
    const int n = wave;
    const int lane = threadIdx.x & 63;
    const int sub = lane >> 3;    // edge slot 0..7
    const int ld = lane & 7;      // lane within edge; head = ld>>1
    const int c0 = ld << 3;       // channel base (8 channels per lane)

    const int start = offs[n] + blockBase[n >> 8];
    const int cnt = counts[n];

    const float4 qa = ld4g(&q[(size_t)n * C + c0]);       // pre-scaled by 0.25
    const float4 qb = ld4g(&q[(size_t)n * C + c0 + 4]);
    float4 ma = make_float4(0.f, 0.f, 0.f, 0.f);
    float4 mb = make_float4(0.f, 0.f, 0.f, 0.f);
    float dsum = 0.f;

    for (int i = sub; i < cnt; i += 16) {
        const bool act1 = (i + 8) < cnt;
        const int src0 = srcs[start + i];
        const int src1 = act1 ? srcs[start + i + 8] : src0;   // safe duplicate
        const unsigned short* kb0 = kv + (size_t)src0 * (L * 2 * C) + c0;
        const unsigned short* kb1 = kv + (size_t)src1 * (L * 2 * C) + c0;

        ushort8v k00 = *(const ushort8v*)(kb0);
        ushort8v k01 = *(const ushort8v*)(kb0 + 2 * C);
        ushort8v k02 = *(const ushort8v*)(kb0 + 4 * C);
        ushort8v k10 = *(const ushort8v*)(kb1);
        ushort8v k11 = *(const ushort8v*)(kb1 + 2 * C);
        ushort8v k12 = *(const ushort8v*)(kb1 + 4 * C);
        ushort8v v00 = *(const ushort8v*)(kb0 + C);
        ushort8v v01 = *(const ushort8v*)(kb0 + 3 * C);
        ushort8v v02 = *(const ushort8v*)(kb0 + 5 * C);
        ushort8v v10 = *(const ushort8v*)(kb1 + C);
        ushort8v v11 = *(const ushort8v*)(kb1 + 3 * C);
        ushort8v v12 = *(const ushort8v*)(kb1 + 5 * C);

        float s00 = dot8(qa, qb, k00);
        float s01 = dot8(qa, qb, k01);
        float s02 = dot8(qa, qb, k02);
        float s10 = dot8(qa, qb, k10);
        float s11 = dot8(qa, qb, k11);
        float s12 = dot8(qa, qb, k12);
        s00 += __shfl_xor(s00, 1); s01 += __shfl_xor(s01, 1); s02 += __shfl_xor(s02, 1);
        s10 += __shfl_xor(s10, 1); s11 += __shfl_xor(s11, 1); s12 += __shfl_xor(s12, 1);

        float e00 = __expf(s00), e01 = __expf(s01), e02 = __expf(s02);
        float ee0 = fmaxf(fmaxf(e00, e01), e02);
        float sc0 = ee0 / (e00 + e01 + e02);
        float w00 = e00 * sc0, w01 = e01 * sc0, w02 = e02 * sc0;

        float e10 = __expf(s10), e11 = __expf(s11), e12 = __expf(s12);
        float ee1 = fmaxf(fmaxf(e10, e11), e12);
        float sc1 = ee1 / (e10 + e11 + e12);
        float w10 = e10 * sc1, w11 = e11 * sc1, w12 = e12 * sc1;
        if (!act1) { w10 = 0.f; w11 = 0.f; w12 = 0.f; ee1 = 0.f; }

        acc8(ma, mb, w00, v00);
        acc8(ma, mb, w01, v01);
        acc8(ma, mb, w02, v02);
        acc8(ma, mb, w10, v10);
        acc8(ma, mb, w11, v11);
        acc8(ma, mb, w12, v12);
        dsum += ee0 + ee1;
    }

    // reduce the 8 edge slots (lane bits 3,4,5)
    #pragma unroll
    for (int m = 8; m <= 32; m <<= 1) {
        ma.x += __shfl_xor(ma.x, m); ma.y += __shfl_xor(ma.y, m);
        ma.z += __shfl_xor(ma.z, m); ma.w += __shfl_xor(ma.w, m);
        mb.x += __shfl_xor(mb.x, m); mb.y += __shfl_xor(mb.y, m);
        mb.z += __shfl_xor(mb.z, m); mb.w += __shfl_xor(mb.w, m);
        dsum += __shfl_xor(dsum, m);
    }

    if (sub == 0) {
        float inv = dsum > 0.f ? 1.f / dsum : 0.f;   // cnt==0 -> zeros (matches ref)
        float4 oa, ob;
        oa.x = ma.x * inv; oa.y = ma.y * inv; oa.z = ma.z * inv; oa.w = ma.w * inv;
        ob.x = mb.x * inv; ob.y = mb.y * inv; ob.z = mb.z * inv; ob.w = mb.w * inv;
        st4g(&acc[(size_t)n * C + c0], oa);
        st4g(&acc[(size_t)n * C + c0 + 4], ob);
    }
}

// ---------------------------------------------------------------------------
// Output projection: out = acc @ Wo.T + bo + current   (acc pre-normalized)
// ---------------------------------------------------------------------------
__global__ __launch_bounds__(256) void out_kernel(
    const float* __restrict__ acc,
    const float* __restrict__ history,
    const float* __restrict__ Wo, const float* __restrict__ bo,
    float* __restrict__ out, int N)
{
    __shared__ float XT[C][CP];
    __shared__ float WT[C][CP];
    __shared__ float bs[C];
    const int tid = threadIdx.x;
    const int rowBase = blockIdx.x * 64;

    #pragma unroll
    for (int j = 0; j < 16; ++j) {
        int idx = tid + (j << 8);
        WT[idx & 63][idx >> 6] = Wo[idx];
    }
    if (tid < C) bs[tid] = bo[tid];

    #pragma unroll
    for (int j = 0; j < 4; ++j) {
        int f4 = tid + (j << 8);
        int r = f4 >> 4;
        int i0 = (f4 & 15) << 2;
        int grow = rowBase + r;
        float4 xv = make_float4(0.f, 0.f, 0.f, 0.f);
        if (grow < N) xv = ld4g(&acc[(size_t)grow * C + i0]);
        XT[i0 + 0][r] = xv.x; XT[i0 + 1][r] = xv.y;
        XT[i0 + 2][r] = xv.z; XT[i0 + 3][r] = xv.w;
    }
    __syncthreads();

    const int lane = tid & 63;
    const int wid = tid >> 6;
    const int r0 = (wid << 4) + ((lane >> 4) << 2);
    const int c0 = (lane & 15) << 2;

    float4 b = *(const float4*)&bs[c0];
    float4 a[4] = { b, b, b, b };
    for (int i = 0; i < C; ++i) {
        float4 xr = *(const float4*)&XT[i][r0];
        float4 w = *(const float4*)&WT[i][c0];
        fma4(a[0], xr.x, w);
        fma4(a[1], xr.y, w);
        fma4(a[2], xr.z, w);
        fma4(a[3], xr.w, w);
    }
    #pragma unroll
    for (int j = 0; j < 4; ++j) {
        int grow = rowBase + r0 + j;
        if (grow < N) {
            float4 cur = ld4g(&history[((size_t)grow * L + (L - 1)) * C + c0]);
            float4 o = a[j];
            o.x += cur.x; o.y += cur.y; o.z += cur.z; o.w += cur.w;
            st4g(&out[(size_t)grow * C + c0], o);
        }
    }
}

extern "C" void kernel_launch(void* const* d_in, const int* in_sizes, int n_in,
                              void* d_out, int out_size, void* d_ws, size_t ws_size,
                              hipStream_t stream)
{
    const float* history = (const float*)d_in[0];
    const int*   ei      = (const int*)d_in[1];
    const float* Wq = (const float*)d_in[2];
    const float* bq = (const float*)d_in[3];
    const float* Wk = (const float*)d_in[4];
    const float* bk = (const float*)d_in[5];
    const float* Wv = (const float*)d_in[6];
    const float* bv = (const float*)d_in[7];
    const float* Wo = (const float*)d_in[8];
    const float* bo = (const float*)d_in[9];
    const int N = in_sizes[0] / (L * C);
    const int E = in_sizes[1] / 2;

    float* ws   = (float*)d_ws;
    float* qbuf = ws;                                   // N*C fp32
    float* accb = qbuf + (size_t)N * C;                 // N*C fp32
    unsigned short* kvbuf = (unsigned short*)(accb + (size_t)N * C);  // N*L*2C bf16
    int* counts    = (int*)(kvbuf + (size_t)N * L * 2 * C);           // N
    int* offs      = counts + N;                        // N
    int* cursor    = offs + N;                          // N
    int* srcs      = cursor + N;                        // E
    int* blockSums = srcs + E;                          // 256
    int* blockBase = blockSums + 256;                   // 256

    hipMemsetAsync(counts, 0, (size_t)N * sizeof(int), stream);

    const int nkv = (N * L + 63) / 64;
    const int nq  = (N + 63) / 64;
    qkv_kernel<<<nkv + nq, 256, 0, stream>>>(history, Wk, bk, Wv, bv, Wq, bq,
                                             kvbuf, qbuf, ei, counts, N, E, nkv);

    const int eb = (E + 255) / 256;
    const int sb = (N + 255) / 256;   // 196 blocks <= 256
    scan1_kernel<<<sb, 256, 0, stream>>>(counts, offs, cursor, blockSums, N);
    scan2_kernel<<<1, 256, 0, stream>>>(blockSums, blockBase, sb);
    scatter_kernel<<<eb, 256, 0, stream>>>(ei, cursor, blockBase, srcs, E);

    gather_kernel<<<(N + 3) / 4, 256, 0, stream>>>(srcs, offs, counts, blockBase,
                                                   qbuf, kvbuf, accb, N);

    out_kernel<<<nq, 256, 0, stream>>>(accb, history, Wo, bo, (float*)d_out, N);
}

// Round 5
// 171.775 us; speedup vs baseline: 4.8709x; 1.3349x over previous
//
#include <hip/hip_runtime.h>

#define DEV __device__ __forceinline__

constexpr int L = 3;
constexpr int C = 64;
constexpr int H = 4;
constexpr int CP = 68;   // padded LDS stride for fp32 GEMM tiles

typedef unsigned short ushort8v __attribute__((ext_vector_type(8)));
typedef short short8v __attribute__((ext_vector_type(8)));          // 8 bf16 (4 VGPR)
typedef float f32x4 __attribute__((ext_vector_type(4)));

DEV float4 ld4g(const float* p) { return *reinterpret_cast<const float4*>(p); }
DEV void st4g(float* p, float4 v) { *reinterpret_cast<float4*>(p) = v; }
DEV void fma4(float4& a, float s, float4 w) {
    a.x = fmaf(s, w.x, a.x); a.y = fmaf(s, w.y, a.y);
    a.z = fmaf(s, w.z, a.z); a.w = fmaf(s, w.w, a.w);
}
DEV float b2f(unsigned short u) {
    union { float f; unsigned int i; } x; x.i = ((unsigned int)u) << 16; return x.f;
}
DEV unsigned short f2b(float f) {   // RNE, values finite/normal here
    unsigned int u = __float_as_uint(f);
    return (unsigned short)((u + 0x7FFFu + ((u >> 16) & 1u)) >> 16);
}
DEV float dot8(float4 a, float4 b, ushort8v k) {
    return a.x*b2f(k[0]) + a.y*b2f(k[1]) + a.z*b2f(k[2]) + a.w*b2f(k[3])
         + b.x*b2f(k[4]) + b.y*b2f(k[5]) + b.z*b2f(k[6]) + b.w*b2f(k[7]);
}
DEV void acc8(float4& A, float4& B, float w, ushort8v v) {
    A.x = fmaf(w, b2f(v[0]), A.x); A.y = fmaf(w, b2f(v[1]), A.y);
    A.z = fmaf(w, b2f(v[2]), A.z); A.w = fmaf(w, b2f(v[3]), A.w);
    B.x = fmaf(w, b2f(v[4]), B.x); B.y = fmaf(w, b2f(v[5]), B.y);
    B.z = fmaf(w, b2f(v[6]), B.z); B.w = fmaf(w, b2f(v[7]), B.w);
}

// ---------------------------------------------------------------------------
// MFMA QKV projection + fused dst-histogram-with-rank (atomicAdd return value
// = edge's rank within its dst group; scatter then needs no atomics).
// KV blocks: k,v = X @ W{k,v}.T + b via mfma_f32_16x16x32_bf16, stored bf16
// packed per node kv[node][t][k:64][v:64]. Q blocks: fp32 out, scaled 0.25.
// Per block: 64 rows x 64 cols; wave wid owns rows wid*16..+15 (4 col-tiles,
// 2 K-steps each). W staged in LDS in fragment order:
//   WL[(k>>3)*512 + col*8 + (k&7)] = bf16(W[col][k])
// A-frag: lane holds X[rbase+(lane&15)][(lane>>4)*8 + j (+32)] (global, cvt).
// C/D: col = lane&15, row = (lane>>4)*4 + reg  (m89-verified mapping).
// ---------------------------------------------------------------------------
__global__ __launch_bounds__(256) void qkv_kernel(
    const float* __restrict__ history,
    const float* __restrict__ Wk, const float* __restrict__ bk,
    const float* __restrict__ Wv, const float* __restrict__ bv,
    const float* __restrict__ Wq, const float* __restrict__ bq,
    unsigned short* __restrict__ kvout, float* __restrict__ qout,
    const int* __restrict__ ei, int* __restrict__ counts, int* __restrict__ rank,
    int N, int E, int nkvBlocks)
{
    __shared__ __align__(16) unsigned short WL[2][4096];

    // fused histogram + rank: one edge per global thread
    {
        int gid = blockIdx.x * 256 + threadIdx.x;
        if (gid < E) rank[gid] = atomicAdd(&counts[ei[E + gid]], 1);
    }

    const bool isKV = (int)blockIdx.x < nkvBlocks;
    const int rowBase = (isKV ? blockIdx.x : (blockIdx.x - nkvBlocks)) * 64;
    const int totalRows = isKV ? N * L : N;
    const int tid = threadIdx.x;

    // stage W into LDS in fragment order (bf16)
    {
        const float* W1 = isKV ? Wk : Wq;
        const int col = tid >> 2;          // 0..63
        const int kc = (tid & 3) << 4;     // 0,16,32,48
        #pragma unroll
        for (int g = 0; g < 2; ++g) {
            int k0 = kc + g * 8;
            ushort8v t;
            #pragma unroll
            for (int j = 0; j < 8; ++j) t[j] = f2b(W1[col * 64 + k0 + j]);
            *(ushort8v*)&WL[0][(k0 >> 3) * 512 + col * 8] = t;
        }
        if (isKV) {
            #pragma unroll
            for (int g = 0; g < 2; ++g) {
                int k0 = kc + g * 8;
                ushort8v t;
                #pragma unroll
                for (int j = 0; j < 8; ++j) t[j] = f2b(Wv[col * 64 + k0 + j]);
                *(ushort8v*)&WL[1][(k0 >> 3) * 512 + col * 8] = t;
            }
        }
    }
    __syncthreads();

    const int lane = tid & 63;
    const int wid = tid >> 6;
    const int rbase = rowBase + wid * 16;
    const int kg = lane >> 4;            // k-group 0..3
    const int kbase = kg << 3;           // 0,8,16,24
    const int bcol = lane & 15;

    // A fragments (clamped row for safe OOB load; stores are guarded)
    const int arow = min(rbase + (lane & 15), totalRows - 1);
    const size_t srcRow = isKV ? (size_t)arow : ((size_t)arow * L + (L - 1));
    const float* xp = &history[srcRow * C];
    short8v a0, a1;
    #pragma unroll
    for (int j = 0; j < 8; ++j) {
        a0[j] = (short)f2b(xp[kbase + j]);
        a1[j] = (short)f2b(xp[32 + kbase + j]);
    }

    const f32x4 zero = {0.f, 0.f, 0.f, 0.f};

    if (isKV) {
        f32x4 aK[4] = {zero, zero, zero, zero};
        f32x4 aV[4] = {zero, zero, zero, zero};
        #pragma unroll
        for (int ct = 0; ct < 4; ++ct) {
            int col = ct * 16 + bcol;
            short8v bk0 = *(const short8v*)&WL[0][(kg) * 512 + col * 8];
            short8v bk1 = *(const short8v*)&WL[0][(4 + kg) * 512 + col * 8];
            short8v bv0 = *(const short8v*)&WL[1][(kg) * 512 + col * 8];
            short8v bv1 = *(const short8v*)&WL[1][(4 + kg) * 512 + col * 8];
            aK[ct] = __builtin_amdgcn_mfma_f32_16x16x32_bf16(a0, bk0, aK[ct], 0, 0, 0);
            aK[ct] = __builtin_amdgcn_mfma_f32_16x16x32_bf16(a1, bk1, aK[ct], 0, 0, 0);
            aV[ct] = __builtin_amdgcn_mfma_f32_16x16x32_bf16(a0, bv0, aV[ct], 0, 0, 0);
            aV[ct] = __builtin_amdgcn_mfma_f32_16x16x32_bf16(a1, bv1, aV[ct], 0, 0, 0);
        }
        #pragma unroll
        for (int ct = 0; ct < 4; ++ct) {
            int col = ct * 16 + bcol;
            float biasK = bk[col];
            float biasV = bv[col];
            #pragma unroll
            for (int i = 0; i < 4; ++i) {
                int grow = rbase + kg * 4 + i;
                if (grow < totalRows) {
                    int node = grow / 3;
                    int t = grow - node * 3;
                    unsigned short* dst = kvout + (size_t)node * (L * 2 * C) + t * (2 * C);
                    dst[col] = f2b(aK[ct][i] + biasK);
                    dst[C + col] = f2b(aV[ct][i] + biasV);
                }
            }
        }
    } else {
        f32x4 aQ[4] = {zero, zero, zero, zero};
        #pragma unroll
        for (int ct = 0; ct < 4; ++ct) {
            int col = ct * 16 + bcol;
            short8v bq0 = *(const short8v*)&WL[0][(kg) * 512 + col * 8];
            short8v bq1 = *(const short8v*)&WL[0][(4 + kg) * 512 + col * 8];
            aQ[ct] = __builtin_amdgcn_mfma_f32_16x16x32_bf16(a0, bq0, aQ[ct], 0, 0, 0);
            aQ[ct] = __builtin_amdgcn_mfma_f32_16x16x32_bf16(a1, bq1, aQ[ct], 0, 0, 0);
        }
        #pragma unroll
        for (int ct = 0; ct < 4; ++ct) {
            int col = ct * 16 + bcol;
            float bias = bq[col];
            #pragma unroll
            for (int i = 0; i < 4; ++i) {
                int grow = rbase + kg * 4 + i;
                if (grow < totalRows)
                    qout[(size_t)grow * C + col] = (aQ[ct][i] + bias) * 0.25f;
            }
        }
    }
}

// ---------------------------------------------------------------------------
// Two-level scan (local offsets + per-256-block bases); consumers fold base.
// ---------------------------------------------------------------------------
__global__ __launch_bounds__(256) void scan1_kernel(
    const int* __restrict__ counts, int* __restrict__ offs,
    int* __restrict__ blockSums, int N)
{
    __shared__ int s[256];
    const int t = threadIdx.x;
    const int gid = blockIdx.x * 256 + t;
    int v = (gid < N) ? counts[gid] : 0;
    s[t] = v;
    __syncthreads();
    for (int o = 1; o < 256; o <<= 1) {
        int x = (t >= o) ? s[t - o] : 0;
        __syncthreads();
        s[t] += x;
        __syncthreads();
    }
    if (gid < N) offs[gid] = s[t] - v;        // exclusive, local to 256-chunk
    if (t == 255) blockSums[blockIdx.x] = s[255];
}

__global__ __launch_bounds__(256) void scan2_kernel(
    const int* __restrict__ blockSums, int* __restrict__ blockBase, int B)
{
    __shared__ int s[256];
    const int t = threadIdx.x;
    int v = (t < B) ? blockSums[t] : 0;
    s[t] = v;
    __syncthreads();
    for (int o = 1; o < 256; o <<= 1) {
        int x = (t >= o) ? s[t - o] : 0;
        __syncthreads();
        s[t] += x;
        __syncthreads();
    }
    blockBase[t] = s[t] - v;                  // exclusive
}

// Atomic-free scatter: position = offs[dst] + base + precomputed rank.
__global__ __launch_bounds__(256) void scatter_kernel(
    const int* __restrict__ ei, const int* __restrict__ offs,
    const int* __restrict__ blockBase, const int* __restrict__ rank,
    int* __restrict__ srcs, int E)
{
    int e = blockIdx.x * 256 + threadIdx.x;
    if (e < E) {
        int c = ei[E + e];
        srcs[offs[c] + blockBase[c >> 8] + rank[e]] = ei[e];
    }
}

// ---------------------------------------------------------------------------
// Atomic-free gather, bf16 kv. One wave per dst node; 8 lanes/edge (8 channels
// each), 8 edge slots in flight. Token softmax over L=3 per head (head = 2
// lanes -> one shfl_xor(1)); edge softmax factored out:
//   acc[n] = (sum msg_e*ee_e)/(sum ee_e), ee = exp(max_t score)
// ---------------------------------------------------------------------------
__global__ __launch_bounds__(256) void gather_kernel(
    const int* __restrict__ srcs,
    const int* __restrict__ offs, const int* __restrict__ counts,
    const int* __restrict__ blockBase,
    const float* __restrict__ q, const unsigned short* __restrict__ kv,
    float* __restrict__ acc, int N)
{
    const int wave = blockIdx.x * 4 + (threadIdx.x >> 6);
    if (wave >= N) return;
    const int n = wave;
    const int lane = threadIdx.x & 63;
    const int sub = lane >> 3;    // edge slot 0..7
    const int ld = lane & 7;      // lane within edge; head = ld>>1
    const int c0 = ld << 3;       // channel base (8 channels per lane)

    const int start = offs[n] + blockBase[n >> 8];
    const int cnt = counts[n];

    const float4 qa = ld4g(&q[(size_t)n * C + c0]);       // pre-scaled by 0.25
    const float4 qb = ld4g(&q[(size_t)n * C + c0 + 4]);
    float4 ma = make_float4(0.f, 0.f, 0.f, 0.f);
    float4 mb = make_float4(0.f, 0.f, 0.f, 0.f);
    float dsum = 0.f;

    for (int i = sub; i < cnt; i += 8) {
        const int src = srcs[start + i];
        const unsigned short* kb = kv + (size_t)src * (L * 2 * C) + c0;
        ushort8v k0 = *(const ushort8v*)(kb);
        ushort8v k1 = *(const ushort8v*)(kb + 2 * C);
        ushort8v k2 = *(const ushort8v*)(kb + 4 * C);

        float s0 = dot8(qa, qb, k0);
        float s1 = dot8(qa, qb, k1);
        float s2 = dot8(qa, qb, k2);
        s0 += __shfl_xor(s0, 1);   // head spans 2 lanes
        s1 += __shfl_xor(s1, 1);
        s2 += __shfl_xor(s2, 1);

        float e0 = __expf(s0), e1 = __expf(s1), e2 = __expf(s2);
        float ee = fmaxf(fmaxf(e0, e1), e2);      // = exp(max token score)
        float sc = ee / (e0 + e1 + e2);
        float w0 = e0 * sc, w1 = e1 * sc, w2 = e2 * sc;

        ushort8v v0 = *(const ushort8v*)(kb + C);
        ushort8v v1 = *(const ushort8v*)(kb + 3 * C);
        ushort8v v2 = *(const ushort8v*)(kb + 5 * C);
        acc8(ma, mb, w0, v0);
        acc8(ma, mb, w1, v1);
        acc8(ma, mb, w2, v2);
        dsum += ee;
    }

    // reduce the 8 edge slots (lane bits 3,4,5)
    #pragma unroll
    for (int m = 8; m <= 32; m <<= 1) {
        ma.x += __shfl_xor(ma.x, m); ma.y += __shfl_xor(ma.y, m);
        ma.z += __shfl_xor(ma.z, m); ma.w += __shfl_xor(ma.w, m);
        mb.x += __shfl_xor(mb.x, m); mb.y += __shfl_xor(mb.y, m);
        mb.z += __shfl_xor(mb.z, m); mb.w += __shfl_xor(mb.w, m);
        dsum += __shfl_xor(dsum, m);
    }

    if (sub == 0) {
        float inv = dsum > 0.f ? 1.f / dsum : 0.f;   // cnt==0 -> zeros (matches ref)
        float4 oa, ob;
        oa.x = ma.x * inv; oa.y = ma.y * inv; oa.z = ma.z * inv; oa.w = ma.w * inv;
        ob.x = mb.x * inv; ob.y = mb.y * inv; ob.z = mb.z * inv; ob.w = mb.w * inv;
        st4g(&acc[(size_t)n * C + c0], oa);
        st4g(&acc[(size_t)n * C + c0 + 4], ob);
    }
}

// ---------------------------------------------------------------------------
// Output projection: out = acc @ Wo.T + bo + current   (acc pre-normalized)
// ---------------------------------------------------------------------------
__global__ __launch_bounds__(256) void out_kernel(
    const float* __restrict__ acc,
    const float* __restrict__ history,
    const float* __restrict__ Wo, const float* __restrict__ bo,
    float* __restrict__ out, int N)
{
    __shared__ float XT[C][CP];
    __shared__ float WT[C][CP];
    __shared__ float bs[C];
    const int tid = threadIdx.x;
    const int rowBase = blockIdx.x * 64;

    #pragma unroll
    for (int j = 0; j < 16; ++j) {
        int idx = tid + (j << 8);
        WT[idx & 63][idx >> 6] = Wo[idx];
    }
    if (tid < C) bs[tid] = bo[tid];

    #pragma unroll
    for (int j = 0; j < 4; ++j) {
        int f4 = tid + (j << 8);
        int r = f4 >> 4;
        int i0 = (f4 & 15) << 2;
        int grow = rowBase + r;
        float4 xv = make_float4(0.f, 0.f, 0.f, 0.f);
        if (grow < N) xv = ld4g(&acc[(size_t)grow * C + i0]);
        XT[i0 + 0][r] = xv.x; XT[i0 + 1][r] = xv.y;
        XT[i0 + 2][r] = xv.z; XT[i0 + 3][r] = xv.w;
    }
    __syncthreads();

    const int lane = tid & 63;
    const int wid = tid >> 6;
    const int r0 = (wid << 4) + ((lane >> 4) << 2);
    const int c0 = (lane & 15) << 2;

    float4 b = *(const float4*)&bs[c0];
    float4 a[4] = { b, b, b, b };
    for (int i = 0; i < C; ++i) {
        float4 xr = *(const float4*)&XT[i][r0];
        float4 w = *(const float4*)&WT[i][c0];
        fma4(a[0], xr.x, w);
        fma4(a[1], xr.y, w);
        fma4(a[2], xr.z, w);
        fma4(a[3], xr.w, w);
    }
    #pragma unroll
    for (int j = 0; j < 4; ++j) {
        int grow = rowBase + r0 + j;
        if (grow < N) {
            float4 cur = ld4g(&history[((size_t)grow * L + (L - 1)) * C + c0]);
            float4 o = a[j];
            o.x += cur.x; o.y += cur.y; o.z += cur.z; o.w += cur.w;
            st4g(&out[(size_t)grow * C + c0], o);
        }
    }
}

extern "C" void kernel_launch(void* const* d_in, const int* in_sizes, int n_in,
                              void* d_out, int out_size, void* d_ws, size_t ws_size,
                              hipStream_t stream)
{
    const float* history = (const float*)d_in[0];
    const int*   ei      = (const int*)d_in[1];
    const float* Wq = (const float*)d_in[2];
    const float* bq = (const float*)d_in[3];
    const float* Wk = (const float*)d_in[4];
    const float* bk = (const float*)d_in[5];
    const float* Wv = (const float*)d_in[6];
    const float* bv = (const float*)d_in[7];
    const float* Wo = (const float*)d_in[8];
    const float* bo = (const float*)d_in[9];
    const int N = in_sizes[0] / (L * C);
    const int E = in_sizes[1] / 2;

    float* ws   = (float*)d_ws;
    float* qbuf = ws;                                   // N*C fp32
    float* accb = qbuf + (size_t)N * C;                 // N*C fp32
    unsigned short* kvbuf = (unsigned short*)(accb + (size_t)N * C);  // N*L*2C bf16
    int* counts    = (int*)(kvbuf + (size_t)N * L * 2 * C);           // N
    int* offs      = counts + N;                        // N
    int* srcs      = offs + N;                          // E
    int* rank      = srcs + E;                          // E
    int* blockSums = rank + E;                          // 256
    int* blockBase = blockSums + 256;                   // 256

    hipMemsetAsync(counts, 0, (size_t)N * sizeof(int), stream);

    const int nkv = (N * L + 63) / 64;
    const int nq  = (N + 63) / 64;
    const int eb  = (E + 255) / 256;
    const int qkvBlocks = (nkv + nq) > eb ? (nkv + nq) : eb;  // must cover all edges
    qkv_kernel<<<qkvBlocks, 256, 0, stream>>>(history, Wk, bk, Wv, bv, Wq, bq,
                                              kvbuf, qbuf, ei, counts, rank,
                                              N, E, nkv);

    const int sb = (N + 255) / 256;   // 196 blocks <= 256
    scan1_kernel<<<sb, 256, 0, stream>>>(counts, offs, blockSums, N);
    scan2_kernel<<<1, 256, 0, stream>>>(blockSums, blockBase, sb);
    scatter_kernel<<<eb, 256, 0, stream>>>(ei, offs, blockBase, rank, srcs, E);

    gather_kernel<<<(N + 3) / 4, 256, 0, stream>>>(srcs, offs, counts, blockBase,
                                                   qbuf, kvbuf, accb, N);

    out_kernel<<<nq, 256, 0, stream>>>(accb, history, Wo, bo, (float*)d_out, N);
}